// Round 11
// baseline (746.983 us; speedup 1.0000x reference)
//
#include <hip/hip_runtime.h>

#define BN 200
#define VN 64
#define HIDD 64
#define FINN 32
#define NSW 10
#define EC 63
#define MNE 73
#define NEPAD 160

typedef unsigned short u16;
typedef unsigned int u32;
typedef __attribute__((ext_vector_type(8))) short bf16x8;
typedef __attribute__((ext_vector_type(4))) float f32x4;

__device__ __forceinline__ float bfu(u16 u) { return __uint_as_float(((u32)u) << 16); }
__device__ __forceinline__ u16 f2bf(float f) {
    u32 x = __float_as_uint(f);
    u32 r = x + 0x7fffu + ((x >> 16) & 1u);
    return (u16)(r >> 16);
}
__device__ __forceinline__ float cvtv(const void* p, int i, int fl) {
    return fl ? bfu(((const u16*)p)[i]) : ((const float*)p)[i];
}

__device__ __forceinline__ float ln_relu64(float e) {
    float s1 = e, s2 = e * e;
#pragma unroll
    for (int m = 1; m < 64; m <<= 1) {
        s1 += __shfl_xor(s1, m);
        s2 += __shfl_xor(s2, m);
    }
    float mean = s1 * 0.015625f;
    float var = fmaxf(s2 * 0.015625f - mean * mean, 0.f);
    return fmaxf((e - mean) * rsqrtf(var + 1e-5f), 0.f);
}

// split 8 consecutive floats into hi/lo bf16 fragments
__device__ __forceinline__ void split8(const float* base, bf16x8* hi, bf16x8* lo) {
    union { bf16x8 v; u16 s[8]; } uh, ul;
#pragma unroll
    for (int j = 0; j < 8; j++) {
        float f = base[j];
        u16 h = f2bf(f);
        uh.s[j] = h;
        ul.s[j] = f2bf(f - bfu(h));
    }
    *hi = uh.v;
    *lo = ul.v;
}

// ==================== prep: CSR/ews/dinv + weight frag-pack (hi+lo) + x convert ====================
struct PrepArgs {
    const void* w[18];
    int eoff[18];
    const void* x;
    const void* A;
    const void* S;
    const void* emb;
    const void* p0Ws;
    const int* eS;
};

__global__ __launch_bounds__(256) void k_prep(PrepArgs pa, float* __restrict__ xP,
                                              u16* __restrict__ wpk,
                                              float* __restrict__ ews, float* __restrict__ dinv,
                                              int* __restrict__ row_ptr, int* __restrict__ colp,
                                              int* __restrict__ vOf, int* __restrict__ sw_eidx,
                                              int xtotal) {
    int t = threadIdx.x;
    int fl = (((const u16*)pa.A)[1] == 0x3F80) ? 1 : 0;
    if (blockIdx.x == 0) {
        __shared__ float connL[4096];
        __shared__ int degL[64], rpS[65];
        for (int i = t; i < 4096; i += 256)
            connL[i] = fminf(cvtv(pa.A, i, fl) + cvtv(pa.S, i, fl), 1.f);
        if (t < 128) {
            int j = t >> 6, k = t & 63;
            float a = 0.f;
            for (int h = 0; h < FINN; h++)
                a += cvtv(pa.emb, j * FINN + h, fl) * cvtv(pa.p0Ws, h * 64 + k, fl);
            ews[(j << 6) + k] = a;
        }
        __syncthreads();
        if (t < 64) {
            int d = 0;
            for (int w = 0; w < 64; w++) if (connL[t * 64 + w] != 0.f) d++;
            degL[t] = d;
            dinv[t] = 1.f / fmaxf((float)d, 1.f);
        }
        __syncthreads();
        if (t == 0) {
            int c = 0;
            for (int v = 0; v < 64; v++) { rpS[v] = c; c += degL[v]; }
            rpS[64] = c;
            for (int v = 0; v <= 64; v++) row_ptr[v] = rpS[v];
        }
        __syncthreads();
        if (t < 64) {
            int pos = rpS[t];
            for (int w = 0; w < 64; w++)
                if (connL[t * 64 + w] != 0.f) {
                    colp[pos] = w | ((cvtv(pa.S, t * 64 + w, fl) != 0.f) ? 256 : 0);
                    vOf[pos] = t;
                    pos++;
                }
        }
        __syncthreads();
        if (t < NEPAD && t >= rpS[64]) { colp[t] = 0; vOf[t] = 0; }
        __syncthreads();
        if (t < NSW) {
            int si = pa.eS[t], sj = pa.eS[NSW + t];
            int idx = 0;
            for (int e = rpS[si]; e < rpS[si + 1]; e++)
                if ((colp[e] & 255) == sj) idx = e;
            sw_eidx[t] = idx;
        }
    } else {
        const int jK[18] = {32,32,32,32, 64,64,64,64,64, 64,64,64,64,64, 192,192,256,256};
        const int jN[18] = {64,64,64,64, 64,64,64,64,64, 64,64,64,64,64, 192,3,256,4};
        const int jnt[18] = {4,4,4,4, 4,4,4,4,4, 4,4,4,4,4, 12,1,16,1};
        int szv[18], dof[18], cum[19];
        int off = 0, c = 0;
        for (int j = 0; j < 18; j++) {
            int s = jnt[j] * (jK[j] >> 5) * 512;
            szv[j] = s; dof[j] = off; cum[j] = c;
            off += 2 * s; c += s;
        }
        cum[18] = c;                      // 158720
        int total = c + xtotal;
        int base = (blockIdx.x - 1) * 256 + t;
        int stride = (gridDim.x - 1) * 256;
        for (int i = base; i < total; i += stride) {
            if (i < c) {
                int j = 0;
                while (j < 17 && i >= cum[j + 1]) j++;
                int rem = i - cum[j];
                int kbn = jK[j] >> 5;
                int nt = rem / (kbn << 9);
                int rem2 = rem - nt * (kbn << 9);
                int kb = rem2 >> 9, r8 = rem2 & 511, ln = r8 >> 3, jj = r8 & 7;
                int k = kb * 32 + ((ln >> 4) << 3) + jj;
                int n = nt * 16 + (ln & 15);
                float val = 0.f;
                if (n < jN[j] && k < jK[j])
                    val = cvtv(pa.w[j], pa.eoff[j] + k * jN[j] + n, fl);
                u16 h = f2bf(val);
                wpk[dof[j] + rem] = h;
                wpk[dof[j] + szv[j] + rem] = f2bf(val - bfu(h));
            } else {
                int i2 = i - c;
                xP[i2] = cvtv(pa.x, i2, fl);
            }
        }
    }
}

// ==================== mega: whole network per batch, everything LDS-resident ====================
#define CSTR 204
#define SSTR 268

__global__ __launch_bounds__(256, 1) void k_mega(
    const float* __restrict__ xP, const u16* __restrict__ wpk,
    const float* __restrict__ ewsG, const float* __restrict__ dinvG,
    const int* __restrict__ row_ptr, const int* __restrict__ colp,
    const int* __restrict__ vOf, const int* __restrict__ sw_eidx,
    const int* __restrict__ eA, const int* __restrict__ eS,
    const void* __restrict__ DinvR, const void* __restrict__ IncpR, const void* __restrict__ InccR,
    const u16* __restrict__ A_u16, void* __restrict__ out_v)
{
    __shared__ float xL[4096];          // 16 KB: node stream x (64x64)
    __shared__ float pj[16384];         // 64 KB: projections I,J,V,U; heads-hid overlay
    __shared__ float sL[NEPAD * 64];    // 40 KB: edge state s (160x64, pad rows zero)
    __shared__ float ewsL[128], dinvL[64], xgL[64], xgP[256];
    __shared__ float cmoL[EC * 3], smoL[NSW * 4];
    __shared__ int rpL[65], colpL[NEPAD], vOfL[NEPAD], swE[NSW];

    int b = blockIdx.x, t = threadIdx.x;
    int lane = t & 63, wid = t >> 6;
    int m = lane & 15, quad = lane >> 4;
    int fl = (A_u16[1] == 0x3F80) ? 1 : 0;

    // ---- init ----
    for (int i = t; i < 65; i += 256) rpL[i] = row_ptr[i];
    for (int i = t; i < NEPAD; i += 256) { colpL[i] = colp[i]; vOfL[i] = vOf[i]; }
    for (int i = t; i < 128; i += 256) ewsL[i] = ewsG[i];
    if (t < 64) dinvL[t] = dinvG[t];
    if (t < NSW) swE[t] = sw_eidx[t];
    for (int i = t; i < 64 * 32; i += 256) xL[(i >> 5) * 64 + (i & 31)] = xP[b * 2048 + i];
    for (int i = t; i < NEPAD * 64; i += 256) sL[i] = 0.f;
    __syncthreads();
    int NE = rpL[64];

    const int oWiA[3] = {0, 24576, 65536};
    const int oWjA[3] = {4096, 32768, 73728};
    const int oVA[3]  = {8192, 40960, 81920};
    const int oUA[3]  = {12288, 49152, 90112};
    const int oWsA[3] = {0, 16384, 57344};

    for (int layer = 0; layer < 3; layer++) {
        int kbn = layer ? 2 : 1;
        // ---- proj: wave wid computes mat wid (I,J,V,U) via split-MFMA ----
        {
            int ofs = (wid == 0 ? oWiA : wid == 1 ? oWjA : wid == 2 ? oVA : oUA)[layer];
            int bsz = kbn * 2048;
            bf16x8 bh[4][2], bl[4][2];
            for (int nt = 0; nt < 4; nt++)
                for (int kb = 0; kb < kbn; kb++) {
                    int o = ofs + ((nt * kbn + kb) << 9) + (lane << 3);
                    bh[nt][kb] = *(const bf16x8*)(wpk + o);
                    bl[nt][kb] = *(const bf16x8*)(wpk + o + bsz);
                }
            float* dst = pj + (wid << 12);
            for (int Mt = 0; Mt < 4; Mt++) {
                f32x4 acc[4];
#pragma unroll
                for (int nt = 0; nt < 4; nt++) acc[nt] = (f32x4){0.f, 0.f, 0.f, 0.f};
                for (int kb = 0; kb < kbn; kb++) {
                    bf16x8 ah, al;
                    split8(&xL[(Mt * 16 + m) * 64 + kb * 32 + quad * 8], &ah, &al);
#pragma unroll
                    for (int nt = 0; nt < 4; nt++) {
                        acc[nt] = __builtin_amdgcn_mfma_f32_16x16x32_bf16(ah, bh[nt][kb], acc[nt], 0, 0, 0);
                        acc[nt] = __builtin_amdgcn_mfma_f32_16x16x32_bf16(al, bh[nt][kb], acc[nt], 0, 0, 0);
                        acc[nt] = __builtin_amdgcn_mfma_f32_16x16x32_bf16(ah, bl[nt][kb], acc[nt], 0, 0, 0);
                    }
                }
#pragma unroll
                for (int nt = 0; nt < 4; nt++)
#pragma unroll
                    for (int r = 0; r < 4; r++)
                        dst[(Mt * 16 + quad * 4 + r) * 64 + (nt << 4) + m] = acc[nt][r];
            }
        }
        __syncthreads();

        // ---- edge phase ----
        if (layer == 0) {
            for (int e = wid; e < NE; e += 4) {
                int cp = colpL[e];
                int w = cp & 255, v = vOfL[e], sidx = (cp >> 8) & 1;
                float ee = ewsL[sidx * 64 + lane] + pj[v * 64 + lane] + pj[4096 + w * 64 + lane];
                sL[e * 64 + lane] = ln_relu64(ee);
            }
        } else {
            int ofsW = oWsA[layer];
            bf16x8 wh[4][2], wl[4][2];
            for (int nt = 0; nt < 4; nt++)
                for (int kb = 0; kb < 2; kb++) {
                    int o = ofsW + (((nt << 1) + kb) << 9) + (lane << 3);
                    wh[nt][kb] = *(const bf16x8*)(wpk + o);
                    wl[nt][kb] = *(const bf16x8*)(wpk + o + 4096);
                }
            for (int Mt = wid; Mt < 10; Mt += 4) {
                f32x4 acc[4];
#pragma unroll
                for (int nt = 0; nt < 4; nt++) acc[nt] = (f32x4){0.f, 0.f, 0.f, 0.f};
                for (int kb = 0; kb < 2; kb++) {
                    bf16x8 ah, al;
                    split8(&sL[(Mt * 16 + m) * 64 + kb * 32 + quad * 8], &ah, &al);
#pragma unroll
                    for (int nt = 0; nt < 4; nt++) {
                        acc[nt] = __builtin_amdgcn_mfma_f32_16x16x32_bf16(ah, wh[nt][kb], acc[nt], 0, 0, 0);
                        acc[nt] = __builtin_amdgcn_mfma_f32_16x16x32_bf16(al, wh[nt][kb], acc[nt], 0, 0, 0);
                        acc[nt] = __builtin_amdgcn_mfma_f32_16x16x32_bf16(ah, wl[nt][kb], acc[nt], 0, 0, 0);
                    }
                }
#pragma unroll
                for (int r = 0; r < 4; r++) {
                    int e = Mt * 16 + (quad << 2) + r;
                    int esafe = (e < NE) ? e : 0;
                    int cp = colpL[esafe];
                    int w = cp & 255, v = vOfL[esafe];
                    float en[4];
                    float s1 = 0.f, s2 = 0.f;
#pragma unroll
                    for (int nt = 0; nt < 4; nt++) {
                        int col = (nt << 4) + m;
                        float val = acc[nt][r] + pj[v * 64 + col] + pj[4096 + w * 64 + col];
                        en[nt] = val;
                        s1 += val; s2 += val * val;
                    }
#pragma unroll
                    for (int mm = 1; mm < 16; mm <<= 1) {
                        s1 += __shfl_xor(s1, mm);
                        s2 += __shfl_xor(s2, mm);
                    }
                    float mean = s1 * 0.015625f;
                    float var = fmaxf(s2 * 0.015625f - mean * mean, 0.f);
                    float rinv = rsqrtf(var + 1e-5f);
                    if (e < NE) {
#pragma unroll
                        for (int nt = 0; nt < 4; nt++) {
                            int col = (nt << 4) + m;
                            float sp = sL[e * 64 + col];
                            sL[e * 64 + col] = sp + fmaxf((en[nt] - mean) * rinv, 0.f);
                        }
                    }
                }
            }
        }
        __syncthreads();

        // ---- gate + mean-agg + node update ----
        for (int v = (wid << 4); v < (wid << 4) + 16; v++) {
            int e0 = rpL[v], e1 = rpL[v + 1];
            float acc = 0.f;
            for (int e = e0; e < e1; e++) {
                int w = colpL[e] & 255;
                acc += pj[8192 + w * 64 + lane] / (1.f + __expf(-sL[e * 64 + lane]));
            }
            float z = pj[12288 + v * 64 + lane] + acc * dinvL[v];
            float h = ln_relu64(z);
            xL[v * 64 + lane] = (layer == 0) ? h : xL[v * 64 + lane] + h;
        }
        __syncthreads();
    }

    // ---- x_g ----
    {
        float a = 0.f;
        for (int v = (wid << 4); v < (wid << 4) + 16; v++) a += xL[v * 64 + lane];
        xgP[wid * 64 + lane] = a;
    }
    __syncthreads();
    if (t < 64) xgL[t] = xgP[t] + xgP[64 + t] + xgP[128 + t] + xgP[192 + t];
    __syncthreads();

    // ---- heads (verified split-precision MFMA), sources in LDS ----
    const u16* c1h = wpk + 98304;  const u16* c1l = wpk + 135168;
    const u16* c2h = wpk + 172032; const u16* c2l = wpk + 175104;
    const u16* s1h = wpk + 178176; const u16* s1l = wpk + 243712;
    const u16* s2h = wpk + 309248; const u16* s2l = wpk + 313344;
    float* hidF = pj;    // overlay: projections dead

    {   // cmlp GEMM1: rows = line edges, K=192 = [x3[ai], x3[aj], xg]
        int e = wid * 16 + m; if (e > 62) e = 62;
        int ai = eA[e], aj = eA[EC + e];
        const float* seg0 = &xL[ai * 64];
        const float* seg1 = &xL[aj * 64];
        const float* seg2 = xgL;
        f32x4 accC[12];
#pragma unroll
        for (int nt = 0; nt < 12; nt++) accC[nt] = (f32x4){0.f, 0.f, 0.f, 0.f};
#pragma unroll
        for (int kb = 0; kb < 6; kb++) {
            int k = kb * 32 + quad * 8;
            const float* base = (k < 64) ? seg0 + k : (k < 128) ? seg1 + (k - 64) : seg2 + (k - 128);
            bf16x8 ah, al;
            split8(base, &ah, &al);
#pragma unroll
            for (int nt = 0; nt < 12; nt++) {
                int o = ((nt * 6 + kb) << 9) + (lane << 3);
                bf16x8 bh = *(const bf16x8*)(c1h + o);
                bf16x8 bl = *(const bf16x8*)(c1l + o);
                accC[nt] = __builtin_amdgcn_mfma_f32_16x16x32_bf16(ah, bh, accC[nt], 0, 0, 0);
                accC[nt] = __builtin_amdgcn_mfma_f32_16x16x32_bf16(al, bh, accC[nt], 0, 0, 0);
                accC[nt] = __builtin_amdgcn_mfma_f32_16x16x32_bf16(ah, bl, accC[nt], 0, 0, 0);
            }
        }
#pragma unroll
        for (int nt = 0; nt < 12; nt++)
#pragma unroll
            for (int r = 0; r < 4; r++)
                hidF[(wid * 16 + quad * 4 + r) * CSTR + nt * 16 + m] = fmaxf(accC[nt][r], 0.f);
    }
    __syncthreads();
    {   // cmlp GEMM2
        f32x4 accD = (f32x4){0.f, 0.f, 0.f, 0.f};
#pragma unroll
        for (int kb = 0; kb < 6; kb++) {
            bf16x8 ah, al;
            split8(&hidF[(wid * 16 + m) * CSTR + kb * 32 + quad * 8], &ah, &al);
            int o = (kb << 9) + (lane << 3);
            bf16x8 bh = *(const bf16x8*)(c2h + o);
            bf16x8 bl = *(const bf16x8*)(c2l + o);
            accD = __builtin_amdgcn_mfma_f32_16x16x32_bf16(ah, bh, accD, 0, 0, 0);
            accD = __builtin_amdgcn_mfma_f32_16x16x32_bf16(al, bh, accD, 0, 0, 0);
            accD = __builtin_amdgcn_mfma_f32_16x16x32_bf16(ah, bl, accD, 0, 0, 0);
        }
#pragma unroll
        for (int r = 0; r < 4; r++) {
            int row = wid * 16 + quad * 4 + r;
            if (row < EC && m < 3)
                cmoL[row * 3 + m] = 1.f / (1.f + __expf(-accD[r]));
        }
    }
    __syncthreads();
    {   // smlp GEMM1: rows = switch edges, K=256 = [s3, x3[si], x3[sj], xg]
        int e2 = (m > 9) ? 9 : m;
        int si = eS[e2], sj = eS[NSW + e2];
        int sw = swE[e2];
        const float* t0 = &sL[sw * 64];
        const float* t1 = &xL[si * 64];
        const float* t2 = &xL[sj * 64];
        const float* t3 = xgL;
        f32x4 accS[4];
#pragma unroll
        for (int q2 = 0; q2 < 4; q2++) accS[q2] = (f32x4){0.f, 0.f, 0.f, 0.f};
#pragma unroll
        for (int kb = 0; kb < 8; kb++) {
            int k = kb * 32 + quad * 8;
            const float* base = (k < 64) ? t0 + k : (k < 128) ? t1 + (k - 64)
                              : (k < 192) ? t2 + (k - 128) : t3 + (k - 192);
            bf16x8 ah, al;
            split8(base, &ah, &al);
#pragma unroll
            for (int q2 = 0; q2 < 4; q2++) {
                int nt = wid * 4 + q2;
                int o = ((nt * 8 + kb) << 9) + (lane << 3);
                bf16x8 bh = *(const bf16x8*)(s1h + o);
                bf16x8 bl = *(const bf16x8*)(s1l + o);
                accS[q2] = __builtin_amdgcn_mfma_f32_16x16x32_bf16(ah, bh, accS[q2], 0, 0, 0);
                accS[q2] = __builtin_amdgcn_mfma_f32_16x16x32_bf16(al, bh, accS[q2], 0, 0, 0);
                accS[q2] = __builtin_amdgcn_mfma_f32_16x16x32_bf16(ah, bl, accS[q2], 0, 0, 0);
            }
        }
#pragma unroll
        for (int q2 = 0; q2 < 4; q2++) {
            int nt = wid * 4 + q2;
#pragma unroll
            for (int r = 0; r < 4; r++)
                hidF[(quad * 4 + r) * SSTR + nt * 16 + m] = fmaxf(accS[q2][r], 0.f);
        }
    }
    __syncthreads();
    if (wid == 0) {   // smlp GEMM2
        f32x4 accT = (f32x4){0.f, 0.f, 0.f, 0.f};
#pragma unroll
        for (int kb = 0; kb < 8; kb++) {
            bf16x8 ah, al;
            split8(&hidF[m * SSTR + kb * 32 + quad * 8], &ah, &al);
            int o = (kb << 9) + (lane << 3);
            bf16x8 bh = *(const bf16x8*)(s2h + o);
            bf16x8 bl = *(const bf16x8*)(s2l + o);
            accT = __builtin_amdgcn_mfma_f32_16x16x32_bf16(ah, bh, accT, 0, 0, 0);
            accT = __builtin_amdgcn_mfma_f32_16x16x32_bf16(al, bh, accT, 0, 0, 0);
            accT = __builtin_amdgcn_mfma_f32_16x16x32_bf16(ah, bl, accT, 0, 0, 0);
        }
#pragma unroll
        for (int r = 0; r < 4; r++) {
            int row = quad * 4 + r;
            if (row < NSW && m < 4)
                smoL[row * 4 + m] = 1.f / (1.f + __expf(-accT[r]));
        }
    }
    __syncthreads();

    // ---- final assembly ----
    if (t < 2 * MNE + VN) {
        float val;
        if (t < MNE) {
            val = (t < EC) ? cmoL[t * 3] - 0.5f : smoL[(t - EC) * 4 + 1] - 0.5f;
        } else if (t < MNE + VN) {
            int i = t - MNE;
            if (i == 0) {
                val = 1.0f;
            } else {
                float acc = 0.f;
                for (int mm = 0; mm < MNE; mm++) {
                    float ip = cvtv(IncpR, i * MNE + mm, fl);
                    float ic = cvtv(InccR, i * MNE + mm, fl);
                    if (ip != 0.f || ic != 0.f) {
                        float vp, vc;
                        if (mm < EC) {
                            vp = 0.9f + 0.2f * cmoL[mm * 3 + 1];
                            vc = 0.9f + 0.2f * cmoL[mm * 3 + 2];
                        } else {
                            vp = 0.9f + 0.2f * smoL[(mm - EC) * 4 + 2];
                            vc = 0.9f + 0.2f * smoL[(mm - EC) * 4 + 3];
                        }
                        acc += ip * vp + ic * vc;
                    }
                }
                val = acc * cvtv(DinvR, i * VN + i, fl);
            }
        } else {
            int mm = t - (MNE + VN);
            val = (mm < EC) ? 1.0f : smoL[(mm - EC) * 4];
        }
        size_t oidx = (size_t)b * (2 * MNE + VN) + t;
        if (fl) ((u16*)out_v)[oidx] = f2bf(val);
        else    ((float*)out_v)[oidx] = val;
    }
}

extern "C" void kernel_launch(void* const* d_in, const int* in_sizes, int n_in,
                              void* d_out, int out_size, void* d_ws, size_t ws_size,
                              hipStream_t stream) {
    const int* eA = (const int*)d_in[21];
    const int* eS = (const int*)d_in[22];

    char* w = (char*)d_ws;
    float* xP   = (float*)w;                         // 409600 f
    u16*   wpk  = (u16*)(w + 409600 * 4);            // 317440 u16
    float* ews  = (float*)(w + 409600 * 4 + 317440 * 2 + 64);   // 64B pad for alignment
    float* dinv = ews + 128;
    int* row_ptr = (int*)(dinv + 64);
    int* colp    = row_ptr + 80;
    int* vOf     = colp + NEPAD;
    int* sw_eidx = vOf + NEPAD;

    PrepArgs pa;
    const int widx[18] = {5, 6, 8, 7, 9, 10, 11, 13, 12, 9, 10, 11, 13, 12, 16, 17, 14, 15};
    const int weoff[18] = {0, 0, 0, 0, 0, 0, 0, 0, 0, 4096, 4096, 4096, 4096, 4096, 0, 0, 0, 0};
    for (int j = 0; j < 18; j++) { pa.w[j] = d_in[widx[j]]; pa.eoff[j] = weoff[j]; }
    pa.x = d_in[0]; pa.A = d_in[1]; pa.S = d_in[2];
    pa.emb = d_in[3]; pa.p0Ws = d_in[4]; pa.eS = eS;

    k_prep<<<2049, 256, 0, stream>>>(pa, xP, wpk, ews, dinv, row_ptr, colp, vOf, sw_eidx,
                                     in_sizes[0]);

    k_mega<<<BN, 256, 0, stream>>>(xP, wpk, ews, dinv, row_ptr, colp, vOf, sw_eidx,
                                   eA, eS, d_in[18], d_in[19], d_in[20],
                                   (const u16*)d_in[1], d_out);
}

// Round 12
// 306.644 us; speedup vs baseline: 2.4360x; 2.4360x over previous
//
#include <hip/hip_runtime.h>

#define BN 200
#define VN 64
#define HIDD 64
#define FINN 32
#define NSW 10
#define EC 63
#define MNE 73
#define NE_MAX 256

typedef unsigned short u16;
typedef unsigned int u32;
typedef __attribute__((ext_vector_type(8))) short bf16x8;
typedef __attribute__((ext_vector_type(4))) float f32x4;

__device__ __forceinline__ float bfu(u16 u) { return __uint_as_float(((u32)u) << 16); }
__device__ __forceinline__ u16 f2bf(float f) {
    u32 x = __float_as_uint(f);
    u32 r = x + 0x7fffu + ((x >> 16) & 1u);
    return (u16)(r >> 16);
}
__device__ __forceinline__ float cvtv(const void* p, int i, int fl) {
    return fl ? bfu(((const u16*)p)[i]) : ((const float*)p)[i];
}

__device__ __forceinline__ float rlane(float v, int h) {
    return __uint_as_float(__builtin_amdgcn_readlane(__float_as_uint(v), h));
}

__device__ __forceinline__ float ln_relu64(float e) {
    float s1 = e, s2 = e * e;
#pragma unroll
    for (int m = 1; m < 64; m <<= 1) {
        s1 += __shfl_xor(s1, m);
        s2 += __shfl_xor(s2, m);
    }
    float mean = s1 * 0.015625f;
    float var = fmaxf(s2 * 0.015625f - mean * mean, 0.f);
    return fmaxf((e - mean) * rsqrtf(var + 1e-5f), 0.f);
}

// split 8 consecutive floats into hi/lo bf16 fragments
__device__ __forceinline__ void split8(const float* base, bf16x8* hi, bf16x8* lo) {
    union { bf16x8 v; u16 s[8]; } uh, ul;
#pragma unroll
    for (int j = 0; j < 8; j++) {
        float f = base[j];
        u16 h = f2bf(f);
        uh.s[j] = h;
        ul.s[j] = f2bf(f - bfu(h));
    }
    *hi = uh.v;
    *lo = ul.v;
}

struct CvtArgs {
    const void* src[21];
    int cnt[21];
};

// ======== prep: block 0 = CSR/ews/dinv/sw_eidx/inc-lists; blocks 1-64 = head pack; rest = convert ========
__global__ __launch_bounds__(256) void k_prep(CvtArgs ca, const int* __restrict__ eA,
                                              const int* __restrict__ eS,
                                              float* __restrict__ pool,
                                              u16* __restrict__ c1h, u16* __restrict__ c1l,
                                              u16* __restrict__ c2h, u16* __restrict__ c2l,
                                              u16* __restrict__ s1h, u16* __restrict__ s1l,
                                              u16* __restrict__ s2h, u16* __restrict__ s2l,
                                              float* __restrict__ ews, float* __restrict__ dinv,
                                              int* __restrict__ row_ptr, int* __restrict__ colp,
                                              int* __restrict__ sw_eidx,
                                              float* __restrict__ dinvD, int* __restrict__ incCnt,
                                              int* __restrict__ incM, int cvt_total) {
    int t = threadIdx.x;
    int fl = (((const u16*)ca.src[1])[1] == 0x3F80) ? 1 : 0;
    if (blockIdx.x == 0) {
        __shared__ float connL[4096];
        __shared__ int degL[64], rpS[65];
        const void* A = ca.src[1];
        const void* S = ca.src[2];
        for (int i = t; i < 4096; i += 256)
            connL[i] = fminf(cvtv(A, i, fl) + cvtv(S, i, fl), 1.f);
        if (t < 128) {
            int j = t >> 6, k = t & 63;
            float a = 0.f;
            for (int h = 0; h < FINN; h++)
                a += cvtv(ca.src[3], j * FINN + h, fl) * cvtv(ca.src[4], h * 64 + k, fl);
            ews[(j << 6) + k] = a;
        }
        __syncthreads();
        if (t < 64) {
            int d = 0;
            for (int w = 0; w < 64; w++) if (connL[t * 64 + w] != 0.f) d++;
            degL[t] = d;
            dinv[t] = 1.f / fmaxf((float)d, 1.f);
        }
        __syncthreads();
        if (t == 0) {
            int c = 0;
            for (int v = 0; v < 64; v++) { rpS[v] = c; c += degL[v]; }
            rpS[64] = c;
            for (int v = 0; v <= 64; v++) row_ptr[v] = rpS[v];
        }
        __syncthreads();
        if (t < 64) {
            int pos = rpS[t];
            for (int w = 0; w < 64; w++)
                if (connL[t * 64 + w] != 0.f)
                    colp[pos++] = w | ((cvtv(S, t * 64 + w, fl) != 0.f) ? 256 : 0);
        }
        __syncthreads();
        if (t < NSW) {
            int si = eS[t], sj = eS[NSW + t];
            int idx = 0;
            for (int e = rpS[si]; e < rpS[si + 1]; e++)
                if ((colp[e] & 255) == sj) idx = e;
            sw_eidx[t] = idx;
        }
        // incidence lists for the v-head + Dinv diagonal
        if (t < 64) {
            dinvD[t] = cvtv(ca.src[18], t * 64 + t, fl);
            int cnt = 0;
            for (int m = 0; m < MNE; m++) {
                int par = (m < EC) ? eA[m] : eS[m - EC];
                int chi = (m < EC) ? eA[EC + m] : eS[NSW + (m - EC)];
                if (par == t && cnt < 8) incM[t * 8 + cnt++] = (m << 1);
                if (chi == t && cnt < 8) incM[t * 8 + cnt++] = (m << 1) | 1;
            }
            incCnt[t] = cnt;
        }
    } else if (blockIdx.x <= 64) {
        // pack head weights (hi+lo split, B-frag order, W2 padded to N=16)
        const int TOT = 36864 + 3072 + 65536 + 4096;
        for (int i = (blockIdx.x - 1) * 256 + t; i < TOT; i += 64 * 256) {
            int idx = i;
            const void* src;
            u16 *dh, *dl;
            int K2, N2, nt, rem;
            if (idx < 36864) {
                nt = idx / 3072; rem = idx - nt * 3072; src = ca.src[16]; dh = c1h + idx; dl = c1l + idx; K2 = 192; N2 = 192;
            } else if (idx < 36864 + 3072) {
                idx -= 36864; nt = 0; rem = idx; src = ca.src[17]; dh = c2h + idx; dl = c2l + idx; K2 = 192; N2 = 3;
            } else if (idx < 36864 + 3072 + 65536) {
                idx -= 36864 + 3072; nt = idx / 4096; rem = idx - nt * 4096; src = ca.src[14]; dh = s1h + idx; dl = s1l + idx; K2 = 256; N2 = 256;
            } else {
                idx -= 36864 + 3072 + 65536; nt = 0; rem = idx; src = ca.src[15]; dh = s2h + idx; dl = s2l + idx; K2 = 256; N2 = 4;
            }
            int kb = rem >> 9, r8 = rem & 511, ln = r8 >> 3, j = r8 & 7;
            int k = kb * 32 + ((ln >> 4) << 3) + j;
            int n = nt * 16 + (ln & 15);
            float val = 0.f;
            if (n < N2 && k < K2) {
                int si = k * N2 + n;
                val = fl ? bfu(((const u16*)src)[si]) : ((const float*)src)[si];
            }
            u16 h = f2bf(val);
            *dh = h;
            *dl = f2bf(val - bfu(h));
        }
    } else {
        // convert all 21 float inputs to fp32 pool
        int base = (blockIdx.x - 65) * 256 + t;
        int stride = (gridDim.x - 65) * 256;
        for (int idx = base; idx < cvt_total; idx += stride) {
            int seg = 0, off = idx;
            while (off >= ca.cnt[seg]) { off -= ca.cnt[seg]; ++seg; }
            pool[idx] = cvtv(ca.src[seg], off, fl);
        }
    }
}

// -------- node transforms, 16 rows/block, readlane broadcasts --------
__global__ __launch_bounds__(256) void k_xw(const float* __restrict__ x, int Hin,
                                            const float* __restrict__ Wi, const float* __restrict__ Wj,
                                            const float* __restrict__ Vw, const float* __restrict__ U,
                                            float* __restrict__ xi, float* __restrict__ xj,
                                            float* __restrict__ xv, float* __restrict__ xu) {
    int t = threadIdx.x, lane = t & 63, wid = t >> 6;
    size_t row0 = (size_t)blockIdx.x * 16;
    const float* W = (wid == 0) ? Wi : (wid == 1) ? Wj : (wid == 2) ? Vw : U;
    float* out = (wid == 0) ? xi : (wid == 1) ? xj : (wid == 2) ? xv : xu;

    float xd[16];
#pragma unroll
    for (int r = 0; r < 16; r++)
        xd[r] = (Hin == 64) ? x[(row0 + r) * 64 + lane]
                            : (lane < 32 ? x[(row0 + r) * 32 + lane] : 0.f);
    float acc[16];
#pragma unroll
    for (int r = 0; r < 16; r++) acc[r] = 0.f;
    for (int h = 0; h < Hin; h++) {
        float wv = W[h * 64 + lane];
#pragma unroll
        for (int r = 0; r < 16; r++) acc[r] += rlane(xd[r], h) * wv;
    }
#pragma unroll
    for (int r = 0; r < 16; r++) out[(row0 + r) * 64 + lane] = acc[r];
}

// -------- sparse edge kernel + fused node update (readlane matvec) --------
__global__ __launch_bounds__(256) void k_edge(
    const float* __restrict__ ews, const float* __restrict__ Ws,
    const int* __restrict__ row_ptr, const int* __restrict__ colp,
    const float* __restrict__ dinv,
    const float* __restrict__ xi, const float* __restrict__ xj,
    const float* __restrict__ xv, const float* __restrict__ xu,
    float* __restrict__ s_edge, float* __restrict__ x_cur, int layer)
{
    int t = threadIdx.x, blk = blockIdx.x;
    int b = blk >> 4, vg = blk & 15;
    int wid = t >> 6, lane = t & 63;
    int v = (vg << 2) + wid;
    size_t rowb = (size_t)b << 6;

    float wreg[64];
    if (layer > 0) {
#pragma unroll
        for (int h = 0; h < 64; h++) wreg[h] = Ws[h * 64 + lane];
    }

    int e0 = __builtin_amdgcn_readfirstlane(row_ptr[v]);
    int e1 = __builtin_amdgcn_readfirstlane(row_ptr[v + 1]);
    float xival = xi[((rowb + v) << 6) + lane];
    float acc = 0.f;

    for (int e = e0; e < e1; e++) {
        int cp = __builtin_amdgcn_readfirstlane(colp[e]);
        int w = cp & 255;
        float xjv = xj[((rowb + w) << 6) + lane];
        float* srow = s_edge + (((size_t)b * NE_MAX + e) << 6);
        float sout;
        if (layer == 0) {
            int sidx = (cp >> 8) & 1;
            float ee = ews[(sidx << 6) + lane] + xival + xjv;
            sout = ln_relu64(ee);
        } else {
            float sp = srow[lane];
            float a = 0.f;
#pragma unroll
            for (int h = 0; h < 64; h++) a += rlane(sp, h) * wreg[h];
            float ee = a + xival + xjv;
            sout = sp + ln_relu64(ee);
        }
        srow[lane] = sout;
        acc += xv[((rowb + w) << 6) + lane] / (1.f + __expf(-sout));
    }
    float mval = acc * dinv[v];

    size_t idx = ((rowb + v) << 6) + lane;
    float z = xu[idx] + mval;
    float h = ln_relu64(z);
    if (layer == 0) x_cur[idx] = h;
    else            x_cur[idx] = x_cur[idx] + h;
}

// -------- fused heads + xg + final: split-precision MFMA, 1 block/batch --------
#define CSTR 204
#define SSTR 268
__global__ __launch_bounds__(256, 1) void k_heads(
    const float* __restrict__ s_edge, const int* __restrict__ sw_eidx,
    const int* __restrict__ eA, const int* __restrict__ eS,
    const float* __restrict__ x3,
    const u16* __restrict__ c1h, const u16* __restrict__ c1l,
    const u16* __restrict__ c2h, const u16* __restrict__ c2l,
    const u16* __restrict__ s1h, const u16* __restrict__ s1l,
    const u16* __restrict__ s2h, const u16* __restrict__ s2l,
    const float* __restrict__ dinvD, const int* __restrict__ incCnt, const int* __restrict__ incM,
    const u16* __restrict__ A_u16, void* __restrict__ out_v)
{
    __shared__ float hidF[64 * CSTR];     // 52.2 KB, reused by smlp phase (16 x SSTR)
    __shared__ float xgL[64], xgP[256];
    __shared__ float cmoL[EC * 3], smoL[NSW * 4];
    int b = blockIdx.x, t = threadIdx.x;
    int lane = t & 63, wid = t >> 6;
    int m = lane & 15, quad = lane >> 4;
    size_t rowb = (size_t)b << 6;
    int fl = (A_u16[1] == 0x3F80) ? 1 : 0;

    // ---- xg = sum over v (in-block) ----
    {
        float a = 0.f;
        for (int v = (wid << 4); v < (wid << 4) + 16; v++)
            a += x3[((rowb + v) << 6) + lane];
        xgP[wid * 64 + lane] = a;
    }
    __syncthreads();
    if (t < 64) xgL[t] = xgP[t] + xgP[64 + t] + xgP[128 + t] + xgP[192 + t];
    __syncthreads();

    // ---- cmlp GEMM1: A rows = edges (wid*16+m), K=192 = [x3[ai], x3[aj], xg] ----
    int e = wid * 16 + m; if (e > 62) e = 62;
    int ai = eA[e], aj = eA[EC + e];
    const float* seg0 = x3 + ((rowb + ai) << 6);
    const float* seg1 = x3 + ((rowb + aj) << 6);
    const float* seg2 = xgL;
    f32x4 accC[12];
#pragma unroll
    for (int nt = 0; nt < 12; nt++) accC[nt] = (f32x4){0.f, 0.f, 0.f, 0.f};
#pragma unroll
    for (int kb = 0; kb < 6; kb++) {
        int k = kb * 32 + quad * 8;
        const float* base = (k < 64) ? seg0 + k : (k < 128) ? seg1 + (k - 64) : seg2 + (k - 128);
        bf16x8 ah, al;
        split8(base, &ah, &al);
#pragma unroll
        for (int nt = 0; nt < 12; nt++) {
            int o = ((nt * 6 + kb) << 9) + (lane << 3);
            bf16x8 bh = *(const bf16x8*)(c1h + o);
            bf16x8 bl = *(const bf16x8*)(c1l + o);
            accC[nt] = __builtin_amdgcn_mfma_f32_16x16x32_bf16(ah, bh, accC[nt], 0, 0, 0);
            accC[nt] = __builtin_amdgcn_mfma_f32_16x16x32_bf16(al, bh, accC[nt], 0, 0, 0);
            accC[nt] = __builtin_amdgcn_mfma_f32_16x16x32_bf16(ah, bl, accC[nt], 0, 0, 0);
        }
    }
#pragma unroll
    for (int nt = 0; nt < 12; nt++)
#pragma unroll
        for (int r = 0; r < 4; r++)
            hidF[(wid * 16 + quad * 4 + r) * CSTR + nt * 16 + m] = fmaxf(accC[nt][r], 0.f);
    __syncthreads();

    // ---- cmlp GEMM2: hid(64x192) @ W2p(192x16) ----
    f32x4 accD = (f32x4){0.f, 0.f, 0.f, 0.f};
#pragma unroll
    for (int kb = 0; kb < 6; kb++) {
        bf16x8 ah, al;
        split8(&hidF[(wid * 16 + m) * CSTR + kb * 32 + quad * 8], &ah, &al);
        int o = (kb << 9) + (lane << 3);
        bf16x8 bh = *(const bf16x8*)(c2h + o);
        bf16x8 bl = *(const bf16x8*)(c2l + o);
        accD = __builtin_amdgcn_mfma_f32_16x16x32_bf16(ah, bh, accD, 0, 0, 0);
        accD = __builtin_amdgcn_mfma_f32_16x16x32_bf16(al, bh, accD, 0, 0, 0);
        accD = __builtin_amdgcn_mfma_f32_16x16x32_bf16(ah, bl, accD, 0, 0, 0);
    }
#pragma unroll
    for (int r = 0; r < 4; r++) {
        int row = wid * 16 + quad * 4 + r;
        if (row < EC && m < 3)
            cmoL[row * 3 + m] = 1.f / (1.f + __expf(-accD[r]));
    }
    __syncthreads();   // all reads of hidF (cmlp) done before smlp overwrites

    // ---- smlp GEMM1: A rows = switch edges (m), K=256 = [s_edge, x3[si], x3[sj], xg] ----
    int e2 = (m > 9) ? 9 : m;
    int si = eS[e2], sj = eS[NSW + e2];
    int sw = sw_eidx[e2];
    const float* t0 = s_edge + (((size_t)b * NE_MAX + sw) << 6);
    const float* t1 = x3 + ((rowb + si) << 6);
    const float* t2 = x3 + ((rowb + sj) << 6);
    const float* t3 = xgL;
    f32x4 accS[4];
#pragma unroll
    for (int q2 = 0; q2 < 4; q2++) accS[q2] = (f32x4){0.f, 0.f, 0.f, 0.f};
#pragma unroll
    for (int kb = 0; kb < 8; kb++) {
        int k = kb * 32 + quad * 8;
        const float* base = (k < 64) ? t0 + k : (k < 128) ? t1 + (k - 64)
                          : (k < 192) ? t2 + (k - 128) : t3 + (k - 192);
        bf16x8 ah, al;
        split8(base, &ah, &al);
#pragma unroll
        for (int q2 = 0; q2 < 4; q2++) {
            int nt = wid * 4 + q2;
            int o = ((nt * 8 + kb) << 9) + (lane << 3);
            bf16x8 bh = *(const bf16x8*)(s1h + o);
            bf16x8 bl = *(const bf16x8*)(s1l + o);
            accS[q2] = __builtin_amdgcn_mfma_f32_16x16x32_bf16(ah, bh, accS[q2], 0, 0, 0);
            accS[q2] = __builtin_amdgcn_mfma_f32_16x16x32_bf16(al, bh, accS[q2], 0, 0, 0);
            accS[q2] = __builtin_amdgcn_mfma_f32_16x16x32_bf16(ah, bl, accS[q2], 0, 0, 0);
        }
    }
#pragma unroll
    for (int q2 = 0; q2 < 4; q2++) {
        int nt = wid * 4 + q2;
#pragma unroll
        for (int r = 0; r < 4; r++)
            hidF[(quad * 4 + r) * SSTR + nt * 16 + m] = fmaxf(accS[q2][r], 0.f);
    }
    __syncthreads();

    // ---- smlp GEMM2: hid(16x256) @ W2p(256x16), wave 0 ----
    if (wid == 0) {
        f32x4 accT = (f32x4){0.f, 0.f, 0.f, 0.f};
#pragma unroll
        for (int kb = 0; kb < 8; kb++) {
            bf16x8 ah, al;
            split8(&hidF[m * SSTR + kb * 32 + quad * 8], &ah, &al);
            int o = (kb << 9) + (lane << 3);
            bf16x8 bh = *(const bf16x8*)(s2h + o);
            bf16x8 bl = *(const bf16x8*)(s2l + o);
            accT = __builtin_amdgcn_mfma_f32_16x16x32_bf16(ah, bh, accT, 0, 0, 0);
            accT = __builtin_amdgcn_mfma_f32_16x16x32_bf16(al, bh, accT, 0, 0, 0);
            accT = __builtin_amdgcn_mfma_f32_16x16x32_bf16(ah, bl, accT, 0, 0, 0);
        }
#pragma unroll
        for (int r = 0; r < 4; r++) {
            int row = quad * 4 + r;
            if (row < NSW && m < 4)
                smoL[row * 4 + m] = 1.f / (1.f + __expf(-accT[r]));
        }
    }
    __syncthreads();

    // ---- final assembly (from LDS + incidence lists) ----
    if (t < 2 * MNE + VN) {
        float val;
        if (t < MNE) {
            val = (t < EC) ? cmoL[t * 3] - 0.5f : smoL[(t - EC) * 4 + 1] - 0.5f;
        } else if (t < MNE + VN) {
            int i = t - MNE;
            if (i == 0) {
                val = 1.0f;
            } else {
                float acc = 0.f;
                int c = incCnt[i];
                for (int q = 0; q < c; q++) {
                    int em = incM[i * 8 + q];
                    int mm = em >> 1, role = em & 1;   // 0 = parent, 1 = child
                    float vv = (mm < EC) ? 0.9f + 0.2f * cmoL[mm * 3 + 1 + role]
                                         : 0.9f + 0.2f * smoL[(mm - EC) * 4 + 2 + role];
                    acc += vv;
                }
                val = acc * dinvD[i];
            }
        } else {
            int mm = t - (MNE + VN);
            val = (mm < EC) ? 1.0f : smoL[(mm - EC) * 4];
        }
        size_t oidx = (size_t)b * (2 * MNE + VN) + t;
        if (fl) ((u16*)out_v)[oidx] = f2bf(val);
        else    ((float*)out_v)[oidx] = val;
    }
}

extern "C" void kernel_launch(void* const* d_in, const int* in_sizes, int n_in,
                              void* d_out, int out_size, void* d_ws, size_t ws_size,
                              hipStream_t stream) {
    const int* eA = (const int*)d_in[21];
    const int* eS = (const int*)d_in[22];

    float* pool = (float*)d_ws;

    int off[22];
    off[0] = 0;
    for (int i = 0; i < 21; i++) off[i + 1] = off[i] + in_sizes[i];
    int cvt_total = off[21];

    const float* P_x    = pool + off[0];
    const float* P_p0Wi = pool + off[5];
    const float* P_p0Wj = pool + off[6];
    const float* P_p0U  = pool + off[7];
    const float* P_p0V  = pool + off[8];
    const float* P_plWs = pool + off[9];
    const float* P_plWi = pool + off[10];
    const float* P_plWj = pool + off[11];
    const float* P_plU  = pool + off[12];
    const float* P_plV  = pool + off[13];

    const int NR = BN * VN * HIDD;           // 819,200
    float* tail = pool + ((cvt_total + 7) & ~7);
    float* xi    = tail;
    float* xj    = xi + NR;
    float* xv    = xj + NR;
    float* xu    = xv + NR;
    float* x_cur = xu + NR;
    float* s_edge = x_cur + NR;              // 200*256*64 floats
    float* xg   = s_edge + (size_t)BN * NE_MAX * 64;   // layout slot kept (unused)
    float* conn = xg + 12800;                // slot kept (unused)
    float* dinv = conn + 4096;
    float* ews  = dinv + 64;
    float* smo  = ews + 128;                 // slots kept
    float* cmo  = smo + 8000;
    u16*   c1h  = (u16*)(cmo + 37800);
    u16*   c1l  = c1h + 36864;
    u16*   c2h  = c1l + 36864;
    u16*   c2l  = c2h + 3072;
    u16*   s1h  = c2l + 3072;
    u16*   s1l  = s1h + 65536;
    u16*   s2h  = s1l + 65536;
    u16*   s2l  = s2h + 4096;
    int*   row_ptr = (int*)(s2l + 4096);
    int*   colp    = row_ptr + 80;
    int*   sw_eidx = colp + NE_MAX;
    float* dinvD   = (float*)(sw_eidx + 16);
    int*   incCnt  = (int*)(dinvD + 64);
    int*   incM    = incCnt + 64;

    CvtArgs ca;
    for (int i = 0; i < 21; i++) { ca.src[i] = d_in[i]; ca.cnt[i] = in_sizes[i]; }

    int cvB = (cvt_total + 255) / 256;
    k_prep<<<65 + cvB, 256, 0, stream>>>(ca, eA, eS, pool,
                                         c1h, c1l, c2h, c2l, s1h, s1l, s2h, s2l,
                                         ews, dinv, row_ptr, colp, sw_eidx,
                                         dinvD, incCnt, incM, cvt_total);

    // layer 0
    k_xw<<<BN * VN / 16, 256, 0, stream>>>(P_x, FINN, P_p0Wi, P_p0Wj, P_p0V, P_p0U, xi, xj, xv, xu);
    k_edge<<<BN * 16, 256, 0, stream>>>(ews, P_plWs, row_ptr, colp, dinv, xi, xj, xv, xu,
                                        s_edge, x_cur, 0);
    // layer 1
    k_xw<<<BN * VN / 16, 256, 0, stream>>>(x_cur, HIDD, P_plWi, P_plWj, P_plV, P_plU, xi, xj, xv, xu);
    k_edge<<<BN * 16, 256, 0, stream>>>(ews, P_plWs, row_ptr, colp, dinv, xi, xj, xv, xu,
                                        s_edge, x_cur, 1);
    // layer 2
    k_xw<<<BN * VN / 16, 256, 0, stream>>>(x_cur, HIDD, P_plWi + 4096, P_plWj + 4096,
                                           P_plV + 4096, P_plU + 4096, xi, xj, xv, xu);
    k_edge<<<BN * 16, 256, 0, stream>>>(ews, P_plWs + 4096, row_ptr, colp, dinv, xi, xj, xv, xu,
                                        s_edge, x_cur, 2);

    k_heads<<<BN, 256, 0, stream>>>(s_edge, sw_eidx, eA, eS, x_cur,
                                    c1h, c1l, c2h, c2l, s1h, s1l, s2h, s2l,
                                    dinvD, incCnt, incM, (const u16*)d_in[1], d_out);
}